// Round 1
// baseline (522.319 us; speedup 1.0000x reference)
//
#include <hip/hip_runtime.h>

// MultiheadCrossAttention: B=4, SQ=SK=2048, D=1024, H=16, HD=64.
// Strategy: bf16 MFMA (16x16x32) everywhere, fp32 accumulate.
//   ws layout: [W16 x4 (8MB)] [q16 16MB] [k16 16MB] [vt16 16MB] [o16 16MB]
//   vt16 stored transposed [bh][hd][sk] so PV B-frags are K-contiguous.
// MFMA layouts (guide-verified): A/B frag: lane holds [m|n=lane&15][k=quad*8+j];
//   C/D: col=lane&15, row=quad*4+reg.

typedef __bf16 bf16_t;
typedef __attribute__((ext_vector_type(4))) __bf16 bf16x4;
typedef __attribute__((ext_vector_type(8))) __bf16 bf16x8;
typedef __attribute__((ext_vector_type(4))) float f32x4;

#define MFMA16(a, b, c) __builtin_amdgcn_mfma_f32_16x16x32_bf16(a, b, c, 0, 0, 0)

// ---------------- weight fp32 -> bf16 conversion ----------------
__global__ void wconv_kernel(const float* __restrict__ Wq, const float* __restrict__ Wk,
                             const float* __restrict__ Wv, const float* __restrict__ Wo,
                             bf16_t* __restrict__ out) {
  const int m = blockIdx.y;
  const float* src = (m == 0) ? Wq : (m == 1) ? Wk : (m == 2) ? Wv : Wo;
  bf16_t* dst = out + (size_t)m * (1024 * 1024);
  const int idx = (blockIdx.x * 256 + threadIdx.x) * 4;
  float4 v = *(const float4*)(src + idx);
  bf16x4 pk;
  pk[0] = (bf16_t)v.x; pk[1] = (bf16_t)v.y; pk[2] = (bf16_t)v.z; pk[3] = (bf16_t)v.w;
  *(bf16x4*)(dst + idx) = pk;
}

// ---------------- GEMM: C[8192,1024] = A[8192,1024] @ W[1024,1024]^T + bias ----
// out_mode: 0 = bf16 row-major, 1 = bf16 V-transposed ([bh][hd][sk]), 2 = fp32
template <bool A_F32>
__global__ __launch_bounds__(256, 2) void gemm_kernel(
    const void* __restrict__ Aptr, const bf16_t* __restrict__ Bw,
    const float* __restrict__ bias, void* __restrict__ outp, const int out_mode) {
  constexpr int K = 1024;
  __shared__ bf16_t As[128][32];
  __shared__ bf16_t Bs[128][32];

  const int tid = threadIdx.x;
  const int lane = tid & 63, wave = tid >> 6;
  const int fm = lane & 15, quad = lane >> 4;
  const int wm = (wave >> 1) * 64, wn = (wave & 1) * 64;
  const int m0 = blockIdx.x * 128, n0 = blockIdx.y * 128;

  f32x4 acc[4][4];
#pragma unroll
  for (int i = 0; i < 4; ++i)
#pragma unroll
    for (int j = 0; j < 4; ++j) acc[i][j] = f32x4{0.f, 0.f, 0.f, 0.f};

  for (int k0 = 0; k0 < K; k0 += 32) {
    if constexpr (A_F32) {
      const float* A = (const float*)Aptr;
#pragma unroll
      for (int i = 0; i < 4; ++i) {
        int c = i * 256 + tid;
        int r = c >> 3, cc = (c & 7) * 4;
        float4 v = *(const float4*)(A + (size_t)(m0 + r) * K + k0 + cc);
        bf16x4 pk;
        pk[0] = (bf16_t)v.x; pk[1] = (bf16_t)v.y; pk[2] = (bf16_t)v.z; pk[3] = (bf16_t)v.w;
        *(bf16x4*)&As[r][cc] = pk;
      }
    } else {
      const bf16_t* A = (const bf16_t*)Aptr;
#pragma unroll
      for (int i = 0; i < 2; ++i) {
        int c = i * 256 + tid;
        int r = c >> 2, cc = (c & 3) * 8;
        *(uint4*)&As[r][cc] = *(const uint4*)(A + (size_t)(m0 + r) * K + k0 + cc);
      }
    }
#pragma unroll
    for (int i = 0; i < 2; ++i) {
      int c = i * 256 + tid;
      int r = c >> 2, cc = (c & 3) * 8;
      *(uint4*)&Bs[r][cc] = *(const uint4*)(Bw + (size_t)(n0 + r) * K + k0 + cc);
    }
    __syncthreads();

    bf16x8 af[4], bfr[4];
#pragma unroll
    for (int i = 0; i < 4; ++i) af[i] = *(const bf16x8*)&As[wm + i * 16 + fm][quad * 8];
#pragma unroll
    for (int j = 0; j < 4; ++j) bfr[j] = *(const bf16x8*)&Bs[wn + j * 16 + fm][quad * 8];
#pragma unroll
    for (int i = 0; i < 4; ++i)
#pragma unroll
      for (int j = 0; j < 4; ++j) acc[i][j] = MFMA16(af[i], bfr[j], acc[i][j]);
    __syncthreads();
  }

  float bval[4];
#pragma unroll
  for (int j = 0; j < 4; ++j) bval[j] = bias[n0 + wn + j * 16 + fm];

#pragma unroll
  for (int i = 0; i < 4; ++i) {
#pragma unroll
    for (int j = 0; j < 4; ++j) {
      const int col = n0 + wn + j * 16 + fm;
#pragma unroll
      for (int r = 0; r < 4; ++r) {
        const int row = m0 + wm + i * 16 + quad * 4 + r;
        const float v = acc[i][j][r] + bval[j];
        if (out_mode == 2) {
          ((float*)outp)[(size_t)row * 1024 + col] = v;
        } else if (out_mode == 0) {
          ((bf16_t*)outp)[(size_t)row * 1024 + col] = (bf16_t)v;
        } else {
          const int bb = row >> 11, sk = row & 2047;
          const int h = col >> 6, hd = col & 63;
          ((bf16_t*)outp)[((size_t)((bb * 16 + h) * 64 + hd) << 11) | sk] = (bf16_t)v;
        }
      }
    }
  }
}

// ---------------- flash attention ----------------
// grid: (16 q-tiles, 64 bh). 4 waves; wave w owns q rows [w*32, w*32+32).
__global__ __launch_bounds__(256, 2) void attn_kernel(
    const bf16_t* __restrict__ q16, const bf16_t* __restrict__ k16,
    const bf16_t* __restrict__ vt16, const int* __restrict__ mask,
    bf16_t* __restrict__ o16) {
  __shared__ bf16_t Qs[128][72];          // pitch 72: 8-lane/bank-run b128 reads
  __shared__ bf16_t KVraw[128 * 72];      // union: K[128][72] / Vt[64][136]
  __shared__ bf16_t Ps[128][136];
  __shared__ float maskAdd[128];
  bf16_t (*Ksh)[72] = (bf16_t(*)[72])KVraw;
  bf16_t (*Vsh)[136] = (bf16_t(*)[136])KVraw;

  const int tid = threadIdx.x;
  const int lane = tid & 63, wave = tid >> 6;
  const int fm = lane & 15, quad = lane >> 4;
  const int qt = blockIdx.x, bh = blockIdx.y;
  const int b = bh >> 4, h = bh & 15;
  const float scale = 0.125f;  // HD^-0.5
  const float L2E = 1.44269504f;

  const bf16_t* qbase = q16 + ((size_t)(b * 2048 + qt * 128)) * 1024 + h * 64;
#pragma unroll
  for (int i = 0; i < 4; ++i) {
    int c = i * 256 + tid;
    int r = c >> 3, cc = (c & 7) * 8;
    *(uint4*)&Qs[r][cc] = *(const uint4*)(qbase + (size_t)r * 1024 + cc);
  }

  f32x4 oacc[2][4];
#pragma unroll
  for (int i = 0; i < 2; ++i)
#pragma unroll
    for (int n = 0; n < 4; ++n) oacc[i][n] = f32x4{0.f, 0.f, 0.f, 0.f};
  float mrun[2][4], lrun[2][4];
#pragma unroll
  for (int i = 0; i < 2; ++i)
#pragma unroll
    for (int r = 0; r < 4; ++r) { mrun[i][r] = -3e38f; lrun[i][r] = 0.f; }

  for (int t = 0; t < 16; ++t) {
    __syncthreads();  // prev PV done before K overwrites KV buffer
    const bf16_t* kbase = k16 + ((size_t)(b * 2048 + t * 128)) * 1024 + h * 64;
#pragma unroll
    for (int i = 0; i < 4; ++i) {
      int c = i * 256 + tid;
      int r = c >> 3, cc = (c & 7) * 8;
      *(uint4*)&Ksh[r][cc] = *(const uint4*)(kbase + (size_t)r * 1024 + cc);
    }
    if (tid < 128) maskAdd[tid] = mask[b * 2048 + t * 128 + tid] ? 0.0f : -1e30f;
    __syncthreads();

    // S = Q K^T  (rows: this wave's 32 q-rows; cols: 128 keys)
    f32x4 sacc[2][8];
#pragma unroll
    for (int i = 0; i < 2; ++i)
#pragma unroll
      for (int j = 0; j < 8; ++j) sacc[i][j] = f32x4{0.f, 0.f, 0.f, 0.f};
    bf16x8 aq[2][2];
#pragma unroll
    for (int i = 0; i < 2; ++i)
#pragma unroll
      for (int ks = 0; ks < 2; ++ks)
        aq[i][ks] = *(const bf16x8*)&Qs[wave * 32 + i * 16 + fm][ks * 32 + quad * 8];
#pragma unroll
    for (int j = 0; j < 8; ++j) {
#pragma unroll
      for (int ks = 0; ks < 2; ++ks) {
        bf16x8 bkf = *(const bf16x8*)&Ksh[j * 16 + fm][ks * 32 + quad * 8];
        sacc[0][j] = MFMA16(aq[0][ks], bkf, sacc[0][j]);
        sacc[1][j] = MFMA16(aq[1][ks], bkf, sacc[1][j]);
      }
    }

    float madd[8];
#pragma unroll
    for (int j = 0; j < 8; ++j) madd[j] = maskAdd[j * 16 + fm];

    // online softmax per row (row = quad*4+r within tile; 16 col-lanes share row)
#pragma unroll
    for (int i = 0; i < 2; ++i) {
#pragma unroll
      for (int r = 0; r < 4; ++r) {
        float s[8];
        float smax = -3e38f;
#pragma unroll
        for (int j = 0; j < 8; ++j) {
          s[j] = sacc[i][j][r] * scale + madd[j];
          smax = fmaxf(smax, s[j]);
        }
#pragma unroll
        for (int off = 1; off < 16; off <<= 1) smax = fmaxf(smax, __shfl_xor(smax, off));
        const float mold = mrun[i][r];
        const float mnew = fmaxf(mold, smax);
        const float alpha = exp2f((mold - mnew) * L2E);
        float rsum = 0.f;
        const int prow = wave * 32 + i * 16 + quad * 4 + r;
#pragma unroll
        for (int j = 0; j < 8; ++j) {
          float p = exp2f((s[j] - mnew) * L2E);
          rsum += p;
          Ps[prow][j * 16 + fm] = (bf16_t)p;
        }
#pragma unroll
        for (int off = 1; off < 16; off <<= 1) rsum += __shfl_xor(rsum, off);
        mrun[i][r] = mnew;
        lrun[i][r] = lrun[i][r] * alpha + rsum;
#pragma unroll
        for (int n = 0; n < 4; ++n) oacc[i][n][r] *= alpha;
      }
    }
    __syncthreads();  // done reading K tile

    // stage Vt tile [64 hd][128 sk]
    const bf16_t* vbase = vt16 + (size_t)bh * 64 * 2048 + t * 128;
#pragma unroll
    for (int i = 0; i < 4; ++i) {
      int c = i * 256 + tid;
      int r = c >> 4, cc = (c & 15) * 8;
      *(uint4*)&Vsh[r][cc] = *(const uint4*)(vbase + (size_t)r * 2048 + cc);
    }
    __syncthreads();

    // O += P V   (A = P [q][sk] from own Ps slab, B = Vt [hd][sk])
#pragma unroll
    for (int ks = 0; ks < 4; ++ks) {
      bf16x8 pa[2];
      pa[0] = *(const bf16x8*)&Ps[wave * 32 + fm][ks * 32 + quad * 8];
      pa[1] = *(const bf16x8*)&Ps[wave * 32 + 16 + fm][ks * 32 + quad * 8];
#pragma unroll
      for (int n = 0; n < 4; ++n) {
        bf16x8 vb = *(const bf16x8*)&Vsh[n * 16 + fm][ks * 32 + quad * 8];
        oacc[0][n] = MFMA16(pa[0], vb, oacc[0][n]);
        oacc[1][n] = MFMA16(pa[1], vb, oacc[1][n]);
      }
    }
  }

  // epilogue: normalize by l, store bf16
#pragma unroll
  for (int i = 0; i < 2; ++i) {
#pragma unroll
    for (int r = 0; r < 4; ++r) {
      const float inv = 1.0f / lrun[i][r];
      const int row = qt * 128 + wave * 32 + i * 16 + quad * 4 + r;
#pragma unroll
      for (int n = 0; n < 4; ++n) {
        const int col = h * 64 + n * 16 + fm;
        o16[((size_t)(b * 2048 + row)) * 1024 + col] = (bf16_t)(oacc[i][n][r] * inv);
      }
    }
  }
}

// ---------------- launch ----------------
extern "C" void kernel_launch(void* const* d_in, const int* in_sizes, int n_in,
                              void* d_out, int out_size, void* d_ws, size_t ws_size,
                              hipStream_t stream) {
  const float* query = (const float*)d_in[0];
  const float* key   = (const float*)d_in[1];
  const float* value = (const float*)d_in[2];
  const int* mask    = (const int*)d_in[3];
  const float* Wq = (const float*)d_in[4];
  const float* bq = (const float*)d_in[5];
  const float* Wk = (const float*)d_in[6];
  const float* bk = (const float*)d_in[7];
  const float* Wv = (const float*)d_in[8];
  const float* bv = (const float*)d_in[9];
  const float* Wo = (const float*)d_in[10];
  const float* bo = (const float*)d_in[11];

  char* ws = (char*)d_ws;
  bf16_t* W16  = (bf16_t*)ws;                          // 4 x 1M elems (8 MB)
  bf16_t* q16  = (bf16_t*)(ws + (size_t)8 * 1024 * 1024);
  bf16_t* k16  = q16 + 8388608;                        // B*S*D elems each
  bf16_t* vt16 = k16 + 8388608;
  bf16_t* o16  = vt16 + 8388608;

  wconv_kernel<<<dim3(1024, 4), 256, 0, stream>>>(Wq, Wk, Wv, Wo, W16);
  gemm_kernel<true><<<dim3(64, 8), 256, 0, stream>>>(query, W16,           bq, q16,  0);
  gemm_kernel<true><<<dim3(64, 8), 256, 0, stream>>>(key,   W16 + 1048576, bk, k16,  0);
  gemm_kernel<true><<<dim3(64, 8), 256, 0, stream>>>(value, W16 + 2097152, bv, vt16, 1);
  attn_kernel<<<dim3(16, 64), 256, 0, stream>>>(q16, k16, vt16, mask, o16);
  gemm_kernel<false><<<dim3(64, 8), 256, 0, stream>>>(o16, W16 + 3145728, bo, d_out, 2);
}